// Round 23
// baseline (109.888 us; speedup 1.0000x reference)
//
#include <hip/hip_runtime.h>
#include <hip/hip_fp16.h>

#define N_NODES 50000
#define KNN     16
#define NEDGE   (N_NODES*KNN)     // 800000
#define NTILE2  (NEDGE/128)       // 6250 tiles of 128 edges (8 nodes)
#define NWT     (N_NODES/16)      // 3125 wave-tiles for kUV
#define NB2     1024              // grid kS1/kS2/kS3
#define SLOPE   0.01f
#define EPS     1e-5f

typedef __attribute__((ext_vector_type(8))) _Float16 f16x8;
typedef __attribute__((ext_vector_type(4))) float f32x4;

__device__ __forceinline__ unsigned short f2h(float f){
  union{_Float16 h; unsigned short u;} v; v.h = (_Float16)f; return v.u;
}
__device__ __forceinline__ unsigned short h2u(_Float16 h){
  union{_Float16 h; unsigned short u;} v; v.h = h; return v.u;
}
__device__ __forceinline__ f32x4 MFMA(f16x8 a, f16x8 b, f32x4 c){
  return __builtin_amdgcn_mfma_f32_16x16x32_f16(a, b, c, 0, 0, 0);
}
__device__ __forceinline__ float lrelu(float v){ return v>=0.f ? v : SLOPE*v; }

// ---- kUV: per-node U = x(A-B), V = xB (fp16); wf1 self-packed per wave -----
__global__ __launch_bounds__(256) void kUV(const float* __restrict__ x,
    const float* __restrict__ W1, unsigned short* __restrict__ Ub,
    unsigned short* __restrict__ Vb)
{
  const int t = threadIdx.x, w = t>>6, l = t&63, lr = l&15, lg = l>>4;
  const int wt = blockIdx.x*4 + w;
  if (wt >= NWT) return;

  f16x8 wfr[16];
#pragma unroll
  for (int f=0;f<16;++f){
    const int ks = f>>2, nf = f&3;
    const int k0 = ks*32 + (lg<<3);
    const int col = nf*16 + lr;
    f16x8 r;
#pragma unroll
    for (int e=0;e<8;++e){
      float v = W1[(size_t)(k0+e)*64 + col];
      if (f < 8) v -= W1[(size_t)(k0+e+64)*64 + col];
      r[e] = (_Float16)v;
    }
    wfr[f] = r;
  }

  const int n0 = wt*16;
  const float* xr = x + (size_t)(n0+lr)*64 + lg*8;
  f16x8 a0, a1;
#pragma unroll
  for (int e=0;e<8;++e){ a0[e] = (_Float16)xr[e]; a1[e] = (_Float16)xr[32+e]; }

  f32x4 aU[4], aV[4];
#pragma unroll
  for (int nf=0;nf<4;++nf){
    aU[nf] = (f32x4){0,0,0,0};
    aU[nf] = MFMA(a0, wfr[nf],    aU[nf]);
    aU[nf] = MFMA(a1, wfr[4+nf],  aU[nf]);
    aV[nf] = (f32x4){0,0,0,0};
    aV[nf] = MFMA(a0, wfr[8+nf],  aV[nf]);
    aV[nf] = MFMA(a1, wfr[12+nf], aV[nf]);
  }
#pragma unroll
  for (int nf=0;nf<4;++nf)
#pragma unroll
    for (int r=0;r<4;++r){
      const size_t o = (size_t)(n0 + 4*lg + r)*64 + 16*nf + lr;
      Ub[o] = f2h(aU[nf][r]);
      Vb[o] = f2h(aV[nf][r]);
    }
}

#define LOADUV(U0,U1,V0,V1, nodeId, srcId)                               \
  {                                                                      \
    const unsigned short* Ur = Ub + (size_t)(nodeId)*64 + lg*8;          \
    const unsigned short* Vr = Vb + (size_t)(srcId)*64  + lg*8;          \
    U0 = *(const f16x8*)(Ur); U1 = *(const f16x8*)(Ur + 32);             \
    V0 = *(const f16x8*)(Vr); V1 = *(const f16x8*)(Vr + 32);             \
  }

// ---- kS1: 2-node ILP; stats of z1 = U + V; blocks 0..3 pack wf2/wf3 --------
__global__ __launch_bounds__(256,4) void kS1(const unsigned short* __restrict__ Ub,
    const unsigned short* __restrict__ Vb, const int* __restrict__ ei,
    const float* __restrict__ W2, const float* __restrict__ W3,
    unsigned short* __restrict__ wf, float* __restrict__ part)
{
  __shared__ float red[4][128];
  const int t = threadIdx.x, w = t>>6, l = t&63, lr = l&15, lg = l>>4;
  const int G = gridDim.x;

  if (blockIdx.x < 4){
    const int idx = blockIdx.x*256 + t;           // 0..1023
    const float* W = (idx < 512) ? W2 : W3;
    const int fi = (idx & 511) >> 6;
    const int ll = idx & 63;
    const int ks = fi >> 2, nf = fi & 3;
    const int k0 = ks*32 + ((ll>>4)<<3);
    const int col = nf*16 + (ll&15);
    unsigned short* o = wf + (size_t)idx*8;
#pragma unroll
    for (int e=0;e<8;++e) o[e] = f2h(W[(size_t)(k0+e)*64 + col]);
  }

  float s[16], q[16];
#pragma unroll
  for (int k=0;k<16;++k){ s[k]=0.f; q[k]=0.f; }

#define ACCST(U0,U1,V0,V1)                                              \
  {                                                                     \
    const f16x8 z0 = U0 + V0, z1 = U1 + V1;                             \
    _Pragma("unroll")                                                   \
    for (int e=0;e<8;++e){ const float zf=(float)z0[e]; s[e]+=zf; q[e]=fmaf(zf,zf,q[e]); } \
    _Pragma("unroll")                                                   \
    for (int e=0;e<8;++e){ const float zf=(float)z1[e]; s[8+e]+=zf; q[8+e]=fmaf(zf,zf,q[8+e]); } \
  }

  int tile = blockIdx.x;
  int srcA = ei[tile*128 + (2*w)*16 + lr];
  int srcB = ei[tile*128 + (2*w+1)*16 + lr];
  for (; tile < NTILE2; tile += G){
    const int nA = tile*8 + 2*w, nB = nA + 1;
    f16x8 uA0,uA1,vA0,vA1, uB0,uB1,vB0,vB1;
    LOADUV(uA0,uA1,vA0,vA1, nA, srcA)
    LOADUV(uB0,uB1,vB0,vB1, nB, srcB)
    const int nt = tile + G;
    if (nt < NTILE2){
      srcA = ei[nt*128 + (2*w)*16 + lr];
      srcB = ei[nt*128 + (2*w+1)*16 + lr];
    }
    ACCST(uA0,uA1,vA0,vA1)
    ACCST(uB0,uB1,vB0,vB1)
  }

#pragma unroll
  for (int k=0;k<16;++k){
    float a=s[k]; a+=__shfl_xor(a,1,64); a+=__shfl_xor(a,2,64);
    a+=__shfl_xor(a,4,64); a+=__shfl_xor(a,8,64); s[k]=a;
    float b=q[k]; b+=__shfl_xor(b,1,64); b+=__shfl_xor(b,2,64);
    b+=__shfl_xor(b,4,64); b+=__shfl_xor(b,8,64); q[k]=b;
  }
  if (lr == 0){
#pragma unroll
    for (int e=0;e<8;++e){
      red[w][8*lg+e]    = s[e];
      red[w][32+8*lg+e] = s[8+e];
      red[w][64+8*lg+e] = q[e];
      red[w][96+8*lg+e] = q[8+e];
    }
  }
  __syncthreads();
  if (t < 128)
    part[(size_t)t*NB2 + blockIdx.x] = red[0][t]+red[1][t]+red[2][t]+red[3][t];
}

// ---- kFin: 64 blocks; writes f32 coefs AND packed fp16 coefs ---------------
__global__ __launch_bounds__(256) void kFin(const float* __restrict__ part,
    const float* __restrict__ g, const float* __restrict__ be,
    float* __restrict__ coefs, unsigned short* __restrict__ coefsH, int nb)
{
  __shared__ float rs[256], rq[256];
  const int c = blockIdx.x, t = threadIdx.x;
  const float* ps = part + (size_t)c*nb;
  const float* pq = part + (size_t)(64+c)*nb;
  float s = 0.f, q = 0.f;
  for (int i=t; i<nb; i+=256){ s += ps[i]; q += pq[i]; }
  rs[t]=s; rq[t]=q;
  __syncthreads();
#pragma unroll
  for (int off=128; off>0; off>>=1){
    if (t < off){ rs[t]+=rs[t+off]; rq[t]+=rq[t+off]; }
    __syncthreads();
  }
  if (t==0){
    const float inv  = 1.0f/(float)NEDGE;
    const float mean = rs[0]*inv;
    const float var  = rq[0]*inv - mean*mean;
    const float a    = g[c]*rsqrtf(var + EPS);
    const float cc   = be[c] - mean*a;
    coefs[c]       = a;
    coefs[64 + c]  = cc;
    coefsH[c]      = f2h(a);
    coefsH[64 + c] = f2h(cc);
  }
}

// packed-fp16 BN1 coefs: four b64 vector loads (no insert-element -> no spill)
#define LOAD_C1                                                         \
  f16x8 A1a, A1b, C1a, C1b;                                             \
  {                                                                     \
    const int kb = lg*8;                                                \
    A1a = *(const f16x8*)(coefsH1 + kb);                                \
    A1b = *(const f16x8*)(coefsH1 + 32 + kb);                           \
    C1a = *(const f16x8*)(coefsH1 + 64 + kb);                           \
    C1b = *(const f16x8*)(coefsH1 + 96 + kb);                           \
  }

// h1 = lrelu(a1*(U+V)+c1), fully packed fp16
#define H1F(h0f, h1f, U0,U1,V0,V1)                                      \
  f16x8 h0f, h1f;                                                       \
  {                                                                     \
    const f16x8 t0 = (U0 + V0) * A1a + C1a;                             \
    const f16x8 t1 = (U1 + V1) * A1b + C1b;                             \
    h0f = __builtin_elementwise_max(t0, t0 * (_Float16)0.01f);          \
    h1f = __builtin_elementwise_max(t1, t1 * (_Float16)0.01f);          \
  }

// ---- kS2: 2-node ILP; h1 = lrelu(bn1(U+V)); z2 = h1@W2; stats2 -------------
__global__ __launch_bounds__(256,4) void kS2(const unsigned short* __restrict__ Ub,
    const unsigned short* __restrict__ Vb, const int* __restrict__ ei,
    const uint4* __restrict__ wfg, const unsigned short* __restrict__ coefsH1,
    float* __restrict__ part)
{
  __shared__ uint4 wlds[512];          // wf2 table, 8 KB
  __shared__ float red[4][128];
  const int t = threadIdx.x, w = t>>6, l = t&63, lr = l&15, lg = l>>4;
  const int G = gridDim.x;
  const f32x4 Z4 = (f32x4){0.f,0.f,0.f,0.f};

  for (int i=t; i<512; i+=256) wlds[i] = wfg[i];
  __syncthreads();
  LOAD_C1

  float sumP[4] = {0,0,0,0}, sqP[4] = {0,0,0,0};

  int tile = blockIdx.x;
  int srcA = ei[tile*128 + (2*w)*16 + lr];
  int srcB = ei[tile*128 + (2*w+1)*16 + lr];
  for (; tile < NTILE2; tile += G){
    const int nA = tile*8 + 2*w, nB = nA + 1;
    f16x8 uA0,uA1,vA0,vA1, uB0,uB1,vB0,vB1;
    LOADUV(uA0,uA1,vA0,vA1, nA, srcA)
    LOADUV(uB0,uB1,vB0,vB1, nB, srcB)
    const int nt = tile + G;
    if (nt < NTILE2){
      srcA = ei[nt*128 + (2*w)*16 + lr];
      srcB = ei[nt*128 + (2*w+1)*16 + lr];
    }

    H1F(hA0, hA1, uA0,uA1,vA0,vA1)
    H1F(hB0, hB1, uB0,uB1,vB0,vB1)

    f32x4 aA[4], aB[4];
#pragma unroll
    for (int nf=0;nf<4;++nf){
      union{uint4 v; f16x8 h;}q0, q1;
      q0.v = wlds[nf*64 + l];  q1.v = wlds[(4+nf)*64 + l];
      aA[nf] = MFMA(hA0, q0.h, Z4);  aA[nf] = MFMA(hA1, q1.h, aA[nf]);
      aB[nf] = MFMA(hB0, q0.h, Z4);  aB[nf] = MFMA(hB1, q1.h, aB[nf]);
    }
#pragma unroll
    for (int nf=0;nf<4;++nf)
#pragma unroll
      for (int r=0;r<4;++r){
        const float v0 = aA[nf][r], v1 = aB[nf][r];
        sumP[nf] += v0 + v1;
        sqP[nf] = fmaf(v0,v0,sqP[nf]);
        sqP[nf] = fmaf(v1,v1,sqP[nf]);
      }
  }

#pragma unroll
  for (int nf=0;nf<4;++nf){
    float s = sumP[nf], q = sqP[nf];
    s += __shfl_xor(s,16,64); s += __shfl_xor(s,32,64);
    q += __shfl_xor(q,16,64); q += __shfl_xor(q,32,64);
    if (l < 16){ red[w][nf*16+l] = s; red[w][64+nf*16+l] = q; }
  }
  __syncthreads();
  if (t < 128)
    part[(size_t)t*NB2 + blockIdx.x] = red[0][t]+red[1][t]+red[2][t]+red[3][t];
}

// ---- kS3: 2-node ILP + 1-deep U/V prefetch; launch_bounds(256,2) unpins ----
// the VGPR budget (LDS already caps occupancy at 4 blocks/CU, so no TLP loss)
__global__ __launch_bounds__(256,2) void kS3(const unsigned short* __restrict__ Ub,
    const unsigned short* __restrict__ Vb, const int* __restrict__ ei,
    const uint4* __restrict__ wfg, const unsigned short* __restrict__ coefsH1,
    const float* __restrict__ coefs2, const float* __restrict__ b3,
    const float* __restrict__ x, float* __restrict__ out)
{
  __shared__ uint4 wlds[1024];                              // wf2|wf3, 16 KB
  __shared__ __align__(16) unsigned short buf[8][16][72];   // per-stream, 18 KB
  const int t = threadIdx.x, w = t>>6, l = t&63, lr = l&15, lg = l>>4;
  const int G = gridDim.x;
  const f32x4 Z4 = (f32x4){0.f,0.f,0.f,0.f};

  for (int i=t; i<1024; i+=256) wlds[i] = wfg[i];
  __syncthreads();
  LOAD_C1

  float a2v[4], c2v[4], bb[4];
#pragma unroll
  for (int nf=0;nf<4;++nf){
    a2v[nf]=coefs2[nf*16+lr]; c2v[nf]=coefs2[64+nf*16+lr];
    bb[nf] = b3[nf*16+lr];
  }

  int tile = blockIdx.x;
  int sA = ei[tile*128 + (2*w)*16 + lr];
  int sB = ei[tile*128 + (2*w+1)*16 + lr];
  f16x8 cuA0,cuA1,cvA0,cvA1, cuB0,cuB1,cvB0,cvB1;
  LOADUV(cuA0,cuA1,cvA0,cvA1, tile*8 + 2*w,     sA)
  LOADUV(cuB0,cuB1,cvB0,cvB1, tile*8 + 2*w + 1, sB)
  {
    const int nt0 = tile + G;
    if (nt0 < NTILE2){
      sA = ei[nt0*128 + (2*w)*16 + lr];
      sB = ei[nt0*128 + (2*w+1)*16 + lr];
    } else { sA = 0; sB = 0; }
  }

  for (; tile < NTILE2; tile += G){
    const int nA = tile*8 + 2*w, nB = nA + 1;
    // issue next tile's U/V loads (addresses ready from prefetched indices)
    const int nt = tile + G;
    const int nnA = (nt < NTILE2) ? nt*8 + 2*w : 0;
    const int nnB = (nt < NTILE2) ? nnA + 1 : 0;
    f16x8 nuA0,nuA1,nvA0,nvA1, nuB0,nuB1,nvB0,nvB1;
    LOADUV(nuA0,nuA1,nvA0,nvA1, nnA, sA)
    LOADUV(nuB0,nuB1,nvB0,nvB1, nnB, sB)
    {
      const int nt2 = tile + 2*G;
      if (nt2 < NTILE2){
        sA = ei[nt2*128 + (2*w)*16 + lr];
        sB = ei[nt2*128 + (2*w+1)*16 + lr];
      } else { sA = 0; sB = 0; }
    }

    H1F(hA0, hA1, cuA0,cuA1,cvA0,cvA1)
    H1F(hB0, hB1, cuB0,cuB1,cvB0,cvB1)

    // GEMM2 (unswapped): D = z2[edge 4lg+r][ch 16nf+lr]; B shared across streams
    f32x4 aA[4], aB[4];
#pragma unroll
    for (int nf=0;nf<4;++nf){
      union{uint4 v; f16x8 h;}q0, q1;
      q0.v = wlds[nf*64 + l];  q1.v = wlds[(4+nf)*64 + l];
      aA[nf] = MFMA(hA0, q0.h, Z4);  aA[nf] = MFMA(hA1, q1.h, aA[nf]);
      aB[nf] = MFMA(hB0, q0.h, Z4);  aB[nf] = MFMA(hB1, q1.h, aB[nf]);
    }
    // BN2 + lrelu -> per-stream transpose buffers (fp16)
#pragma unroll
    for (int nf=0;nf<4;++nf)
#pragma unroll
      for (int r=0;r<4;++r){
        buf[2*w  ][4*lg+r][16*nf+lr] = h2u((_Float16)lrelu(fmaf(a2v[nf], aA[nf][r], c2v[nf])));
        buf[2*w+1][4*lg+r][16*nf+lr] = h2u((_Float16)lrelu(fmaf(a2v[nf], aB[nf][r], c2v[nf])));
      }
    const f16x8 gA0 = *(const f16x8*)&buf[2*w  ][lr][8*lg];
    const f16x8 gA1 = *(const f16x8*)&buf[2*w  ][lr][32+8*lg];
    const f16x8 gB0 = *(const f16x8*)&buf[2*w+1][lr][8*lg];
    const f16x8 gB1 = *(const f16x8*)&buf[2*w+1][lr][32+8*lg];

    f32x4 cA[4], cB[4];
#pragma unroll
    for (int nf=0;nf<4;++nf){
      union{uint4 v; f16x8 h;}q0, q1;
      q0.v = wlds[512 + nf*64 + l];  q1.v = wlds[512 + (4+nf)*64 + l];
      cA[nf] = MFMA(gA0, q0.h, Z4);  cA[nf] = MFMA(gA1, q1.h, cA[nf]);
      cB[nf] = MFMA(gB0, q0.h, Z4);  cB[nf] = MFMA(gB1, q1.h, cB[nf]);
    }

    // segmax over each node's 16 edges; bias after max; residual
#pragma unroll
    for (int nf=0;nf<4;++nf){
      float mA = fmaxf(fmaxf(cA[nf][0],cA[nf][1]), fmaxf(cA[nf][2],cA[nf][3]));
      mA = fmaxf(mA, __shfl_xor(mA,16,64));
      mA = fmaxf(mA, __shfl_xor(mA,32,64));
      float mB = fmaxf(fmaxf(cB[nf][0],cB[nf][1]), fmaxf(cB[nf][2],cB[nf][3]));
      mB = fmaxf(mB, __shfl_xor(mB,16,64));
      mB = fmaxf(mB, __shfl_xor(mB,32,64));
      if (l < 16){
        const float xA = x[(size_t)nA*64 + nf*16 + l];
        out[(size_t)nA*64 + nf*16 + l] = lrelu(mA + bb[nf] + xA);
        const float xB = x[(size_t)nB*64 + nf*16 + l];
        out[(size_t)nB*64 + nf*16 + l] = lrelu(mB + bb[nf] + xB);
      }
    }

    cuA0=nuA0; cuA1=nuA1; cvA0=nvA0; cvA1=nvA1;
    cuB0=nuB0; cuB1=nuB1; cvB0=nvB0; cvB1=nvB1;
  }
}

extern "C" void kernel_launch(void* const* d_in, const int* in_sizes, int n_in,
                              void* d_out, int out_size, void* d_ws, size_t ws_size,
                              hipStream_t stream) {
  const float* x   = (const float*)d_in[0];
  const int*   ei  = (const int*)d_in[1];
  const float* W1  = (const float*)d_in[2];
  const float* g1  = (const float*)d_in[4];
  const float* be1 = (const float*)d_in[5];
  const float* W2  = (const float*)d_in[6];
  const float* g2  = (const float*)d_in[8];
  const float* be2 = (const float*)d_in[9];
  const float* W3  = (const float*)d_in[10];
  const float* b3  = (const float*)d_in[11];
  float* out = (float*)d_out;

  // ws: coefs 1KB | coefsH 1KB | part1 512KB | part2 512KB | wfb 16KB | U | V
  float*          coefs  = (float*)d_ws;
  unsigned short* coefsH = (unsigned short*)((char*)d_ws + 1024);
  float*          part1  = (float*)((char*)d_ws + 2048);
  float*          part2  = part1 + (size_t)NB2*128;
  unsigned short* wfb    = (unsigned short*)((char*)part2 + (size_t)NB2*128*4);
  unsigned short* Ub     = (unsigned short*)((char*)wfb + 16384);
  unsigned short* Vb     = Ub + (size_t)N_NODES*64;

  kUV<<<(NWT+3)/4, 256, 0, stream>>>(x, W1, Ub, Vb);
  kS1<<<NB2, 256, 0, stream>>>(Ub, Vb, ei, W2, W3, wfb, part1);
  kFin<<<64, 256, 0, stream>>>(part1, g1, be1, coefs, coefsH, NB2);
  kS2<<<NB2, 256, 0, stream>>>(Ub, Vb, ei, (const uint4*)wfb, coefsH, part2);
  kFin<<<64, 256, 0, stream>>>(part2, g2, be2, coefs + 128, coefsH + 128, NB2);
  kS3<<<NB2, 256, 0, stream>>>(Ub, Vb, ei, (const uint4*)wfb, coefsH,
                               coefs + 128, b3, x, out);
}

// Round 24
// 99.141 us; speedup vs baseline: 1.1084x; 1.1084x over previous
//
#include <hip/hip_runtime.h>
#include <hip/hip_fp16.h>

#define N_NODES 50000
#define KNN     16
#define NEDGE   (N_NODES*KNN)     // 800000
#define NTILE2  (NEDGE/128)       // 6250 tiles of 128 edges (8 nodes)
#define NWT     (N_NODES/16)      // 3125 wave-tiles for kUV
#define NB2     1024              // grid kS1/kS2/kS3
#define SLOPE   0.01f
#define EPS     1e-5f

typedef __attribute__((ext_vector_type(8))) _Float16 f16x8;
typedef __attribute__((ext_vector_type(4))) float f32x4;

__device__ __forceinline__ unsigned short f2h(float f){
  union{_Float16 h; unsigned short u;} v; v.h = (_Float16)f; return v.u;
}
__device__ __forceinline__ unsigned short h2u(_Float16 h){
  union{_Float16 h; unsigned short u;} v; v.h = h; return v.u;
}
__device__ __forceinline__ f32x4 MFMA(f16x8 a, f16x8 b, f32x4 c){
  return __builtin_amdgcn_mfma_f32_16x16x32_f16(a, b, c, 0, 0, 0);
}
__device__ __forceinline__ float lrelu(float v){ return v>=0.f ? v : SLOPE*v; }

// ---- kUV: per-node U = x(A-B), V = xB (fp16); wf1 self-packed per wave -----
__global__ __launch_bounds__(256) void kUV(const float* __restrict__ x,
    const float* __restrict__ W1, unsigned short* __restrict__ Ub,
    unsigned short* __restrict__ Vb)
{
  const int t = threadIdx.x, w = t>>6, l = t&63, lr = l&15, lg = l>>4;
  const int wt = blockIdx.x*4 + w;
  if (wt >= NWT) return;

  // self-pack wf1 fragments (frags 0..7 = A-B, 8..15 = B); W1 is L1/L2-hot
  f16x8 wfr[16];
#pragma unroll
  for (int f=0;f<16;++f){
    const int ks = f>>2, nf = f&3;
    const int k0 = ks*32 + (lg<<3);
    const int col = nf*16 + lr;
    f16x8 r;
#pragma unroll
    for (int e=0;e<8;++e){
      float v = W1[(size_t)(k0+e)*64 + col];
      if (f < 8) v -= W1[(size_t)(k0+e+64)*64 + col];
      r[e] = (_Float16)v;
    }
    wfr[f] = r;
  }

  const int n0 = wt*16;
  const float* xr = x + (size_t)(n0+lr)*64 + lg*8;
  f16x8 a0, a1;
#pragma unroll
  for (int e=0;e<8;++e){ a0[e] = (_Float16)xr[e]; a1[e] = (_Float16)xr[32+e]; }

  f32x4 aU[4], aV[4];
#pragma unroll
  for (int nf=0;nf<4;++nf){
    aU[nf] = (f32x4){0,0,0,0};
    aU[nf] = MFMA(a0, wfr[nf],    aU[nf]);
    aU[nf] = MFMA(a1, wfr[4+nf],  aU[nf]);
    aV[nf] = (f32x4){0,0,0,0};
    aV[nf] = MFMA(a0, wfr[8+nf],  aV[nf]);
    aV[nf] = MFMA(a1, wfr[12+nf], aV[nf]);
  }
#pragma unroll
  for (int nf=0;nf<4;++nf)
#pragma unroll
    for (int r=0;r<4;++r){
      const size_t o = (size_t)(n0 + 4*lg + r)*64 + 16*nf + lr;
      Ub[o] = f2h(aU[nf][r]);
      Vb[o] = f2h(aV[nf][r]);
    }
}

#define LOADUV(U0,U1,V0,V1, nodeId, srcId)                               \
  {                                                                      \
    const unsigned short* Ur = Ub + (size_t)(nodeId)*64 + lg*8;          \
    const unsigned short* Vr = Vb + (size_t)(srcId)*64  + lg*8;          \
    U0 = *(const f16x8*)(Ur); U1 = *(const f16x8*)(Ur + 32);             \
    V0 = *(const f16x8*)(Vr); V1 = *(const f16x8*)(Vr + 32);             \
  }

// ---- kS1: 2-node ILP; stats of z1 = U + V; blocks 0..3 pack wf2/wf3 --------
__global__ __launch_bounds__(256,4) void kS1(const unsigned short* __restrict__ Ub,
    const unsigned short* __restrict__ Vb, const int* __restrict__ ei,
    const float* __restrict__ W2, const float* __restrict__ W3,
    unsigned short* __restrict__ wf, float* __restrict__ part)
{
  __shared__ float red[4][128];
  const int t = threadIdx.x, w = t>>6, l = t&63, lr = l&15, lg = l>>4;
  const int G = gridDim.x;

  // blocks 0..3 pack the 1024 wf2|wf3 fragment entries (read by kS2/kS3)
  if (blockIdx.x < 4){
    const int idx = blockIdx.x*256 + t;           // 0..1023
    const float* W = (idx < 512) ? W2 : W3;
    const int fi = (idx & 511) >> 6;
    const int ll = idx & 63;
    const int ks = fi >> 2, nf = fi & 3;
    const int k0 = ks*32 + ((ll>>4)<<3);
    const int col = nf*16 + (ll&15);
    unsigned short* o = wf + (size_t)idx*8;
#pragma unroll
    for (int e=0;e<8;++e) o[e] = f2h(W[(size_t)(k0+e)*64 + col]);
  }

  float s[16], q[16];
#pragma unroll
  for (int k=0;k<16;++k){ s[k]=0.f; q[k]=0.f; }

#define ACCST(U0,U1,V0,V1)                                              \
  {                                                                     \
    const f16x8 z0 = U0 + V0, z1 = U1 + V1;                             \
    _Pragma("unroll")                                                   \
    for (int e=0;e<8;++e){ const float zf=(float)z0[e]; s[e]+=zf; q[e]=fmaf(zf,zf,q[e]); } \
    _Pragma("unroll")                                                   \
    for (int e=0;e<8;++e){ const float zf=(float)z1[e]; s[8+e]+=zf; q[8+e]=fmaf(zf,zf,q[8+e]); } \
  }

  int tile = blockIdx.x;
  int srcA = ei[tile*128 + (2*w)*16 + lr];
  int srcB = ei[tile*128 + (2*w+1)*16 + lr];
  for (; tile < NTILE2; tile += G){
    const int nA = tile*8 + 2*w, nB = nA + 1;
    f16x8 uA0,uA1,vA0,vA1, uB0,uB1,vB0,vB1;
    LOADUV(uA0,uA1,vA0,vA1, nA, srcA)
    LOADUV(uB0,uB1,vB0,vB1, nB, srcB)
    const int nt = tile + G;
    if (nt < NTILE2){
      srcA = ei[nt*128 + (2*w)*16 + lr];
      srcB = ei[nt*128 + (2*w+1)*16 + lr];
    }
    ACCST(uA0,uA1,vA0,vA1)
    ACCST(uB0,uB1,vB0,vB1)
  }

#pragma unroll
  for (int k=0;k<16;++k){
    float a=s[k]; a+=__shfl_xor(a,1,64); a+=__shfl_xor(a,2,64);
    a+=__shfl_xor(a,4,64); a+=__shfl_xor(a,8,64); s[k]=a;
    float b=q[k]; b+=__shfl_xor(b,1,64); b+=__shfl_xor(b,2,64);
    b+=__shfl_xor(b,4,64); b+=__shfl_xor(b,8,64); q[k]=b;
  }
  if (lr == 0){
#pragma unroll
    for (int e=0;e<8;++e){
      red[w][8*lg+e]    = s[e];
      red[w][32+8*lg+e] = s[8+e];
      red[w][64+8*lg+e] = q[e];
      red[w][96+8*lg+e] = q[8+e];
    }
  }
  __syncthreads();
  if (t < 128)
    part[(size_t)t*NB2 + blockIdx.x] = red[0][t]+red[1][t]+red[2][t]+red[3][t];
}

// ---- kFin: 64 blocks; writes f32 coefs AND packed fp16 coefs ---------------
__global__ __launch_bounds__(256) void kFin(const float* __restrict__ part,
    const float* __restrict__ g, const float* __restrict__ be,
    float* __restrict__ coefs, unsigned short* __restrict__ coefsH, int nb)
{
  __shared__ float rs[256], rq[256];
  const int c = blockIdx.x, t = threadIdx.x;
  const float* ps = part + (size_t)c*nb;
  const float* pq = part + (size_t)(64+c)*nb;
  float s = 0.f, q = 0.f;
  for (int i=t; i<nb; i+=256){ s += ps[i]; q += pq[i]; }
  rs[t]=s; rq[t]=q;
  __syncthreads();
#pragma unroll
  for (int off=128; off>0; off>>=1){
    if (t < off){ rs[t]+=rs[t+off]; rq[t]+=rq[t+off]; }
    __syncthreads();
  }
  if (t==0){
    const float inv  = 1.0f/(float)NEDGE;
    const float mean = rs[0]*inv;
    const float var  = rq[0]*inv - mean*mean;
    const float a    = g[c]*rsqrtf(var + EPS);
    const float cc   = be[c] - mean*a;
    coefs[c]       = a;
    coefs[64 + c]  = cc;
    coefsH[c]      = f2h(a);
    coefsH[64 + c] = f2h(cc);
  }
}

// packed-fp16 BN1 coefs: four b64 vector loads (no insert-element -> no spill)
#define LOAD_C1                                                         \
  f16x8 A1a, A1b, C1a, C1b;                                             \
  {                                                                     \
    const int kb = lg*8;                                                \
    A1a = *(const f16x8*)(coefsH1 + kb);                                \
    A1b = *(const f16x8*)(coefsH1 + 32 + kb);                           \
    C1a = *(const f16x8*)(coefsH1 + 64 + kb);                           \
    C1b = *(const f16x8*)(coefsH1 + 96 + kb);                           \
  }

// h1 = lrelu(a1*(U+V)+c1), fully packed fp16
#define H1F(h0f, h1f, U0,U1,V0,V1)                                      \
  f16x8 h0f, h1f;                                                       \
  {                                                                     \
    const f16x8 t0 = (U0 + V0) * A1a + C1a;                             \
    const f16x8 t1 = (U1 + V1) * A1b + C1b;                             \
    h0f = __builtin_elementwise_max(t0, t0 * (_Float16)0.01f);          \
    h1f = __builtin_elementwise_max(t1, t1 * (_Float16)0.01f);          \
  }

// ---- kS2: 2-node ILP; h1 = lrelu(bn1(U+V)); z2 = h1@W2; stats2 -------------
__global__ __launch_bounds__(256,4) void kS2(const unsigned short* __restrict__ Ub,
    const unsigned short* __restrict__ Vb, const int* __restrict__ ei,
    const uint4* __restrict__ wfg, const unsigned short* __restrict__ coefsH1,
    float* __restrict__ part)
{
  __shared__ uint4 wlds[512];          // wf2 table, 8 KB
  __shared__ float red[4][128];
  const int t = threadIdx.x, w = t>>6, l = t&63, lr = l&15, lg = l>>4;
  const int G = gridDim.x;
  const f32x4 Z4 = (f32x4){0.f,0.f,0.f,0.f};

  for (int i=t; i<512; i+=256) wlds[i] = wfg[i];
  __syncthreads();
  LOAD_C1

  float sumP[4] = {0,0,0,0}, sqP[4] = {0,0,0,0};

  int tile = blockIdx.x;
  int srcA = ei[tile*128 + (2*w)*16 + lr];
  int srcB = ei[tile*128 + (2*w+1)*16 + lr];
  for (; tile < NTILE2; tile += G){
    const int nA = tile*8 + 2*w, nB = nA + 1;
    f16x8 uA0,uA1,vA0,vA1, uB0,uB1,vB0,vB1;
    LOADUV(uA0,uA1,vA0,vA1, nA, srcA)
    LOADUV(uB0,uB1,vB0,vB1, nB, srcB)
    const int nt = tile + G;
    if (nt < NTILE2){
      srcA = ei[nt*128 + (2*w)*16 + lr];
      srcB = ei[nt*128 + (2*w+1)*16 + lr];
    }

    H1F(hA0, hA1, uA0,uA1,vA0,vA1)
    H1F(hB0, hB1, uB0,uB1,vB0,vB1)

    f32x4 aA[4], aB[4];
#pragma unroll
    for (int nf=0;nf<4;++nf){
      union{uint4 v; f16x8 h;}q0, q1;
      q0.v = wlds[nf*64 + l];  q1.v = wlds[(4+nf)*64 + l];
      aA[nf] = MFMA(hA0, q0.h, Z4);  aA[nf] = MFMA(hA1, q1.h, aA[nf]);
      aB[nf] = MFMA(hB0, q0.h, Z4);  aB[nf] = MFMA(hB1, q1.h, aB[nf]);
    }
#pragma unroll
    for (int nf=0;nf<4;++nf)
#pragma unroll
      for (int r=0;r<4;++r){
        const float v0 = aA[nf][r], v1 = aB[nf][r];
        sumP[nf] += v0 + v1;
        sqP[nf] = fmaf(v0,v0,sqP[nf]);
        sqP[nf] = fmaf(v1,v1,sqP[nf]);
      }
  }

#pragma unroll
  for (int nf=0;nf<4;++nf){
    float s = sumP[nf], q = sqP[nf];
    s += __shfl_xor(s,16,64); s += __shfl_xor(s,32,64);
    q += __shfl_xor(q,16,64); q += __shfl_xor(q,32,64);
    if (l < 16){ red[w][nf*16+l] = s; red[w][64+nf*16+l] = q; }
  }
  __syncthreads();
  if (t < 128)
    part[(size_t)t*NB2 + blockIdx.x] = red[0][t]+red[1][t]+red[2][t]+red[3][t];
}

// ---- kS3: 2-node ILP; h1 -> z2 -> BN2+lrelu -> z3 -> segmax -> out ---------
__global__ __launch_bounds__(256,4) void kS3(const unsigned short* __restrict__ Ub,
    const unsigned short* __restrict__ Vb, const int* __restrict__ ei,
    const uint4* __restrict__ wfg, const unsigned short* __restrict__ coefsH1,
    const float* __restrict__ coefs2, const float* __restrict__ b3,
    const float* __restrict__ x, float* __restrict__ out)
{
  __shared__ uint4 wlds[1024];                              // wf2|wf3, 16 KB
  __shared__ __align__(16) unsigned short buf[8][16][72];   // per-stream, 18 KB
  const int t = threadIdx.x, w = t>>6, l = t&63, lr = l&15, lg = l>>4;
  const int G = gridDim.x;
  const f32x4 Z4 = (f32x4){0.f,0.f,0.f,0.f};

  for (int i=t; i<1024; i+=256) wlds[i] = wfg[i];
  __syncthreads();
  LOAD_C1

  float a2v[4], c2v[4], bb[4];
#pragma unroll
  for (int nf=0;nf<4;++nf){
    a2v[nf]=coefs2[nf*16+lr]; c2v[nf]=coefs2[64+nf*16+lr];
    bb[nf] = b3[nf*16+lr];
  }

  int tile = blockIdx.x;
  int srcA = ei[tile*128 + (2*w)*16 + lr];
  int srcB = ei[tile*128 + (2*w+1)*16 + lr];
  for (; tile < NTILE2; tile += G){
    const int nA = tile*8 + 2*w, nB = nA + 1;
    f16x8 uA0,uA1,vA0,vA1, uB0,uB1,vB0,vB1;
    LOADUV(uA0,uA1,vA0,vA1, nA, srcA)
    LOADUV(uB0,uB1,vB0,vB1, nB, srcB)
    const int nt = tile + G;
    if (nt < NTILE2){
      srcA = ei[nt*128 + (2*w)*16 + lr];
      srcB = ei[nt*128 + (2*w+1)*16 + lr];
    }

    H1F(hA0, hA1, uA0,uA1,vA0,vA1)
    H1F(hB0, hB1, uB0,uB1,vB0,vB1)

    // GEMM2 (unswapped): D = z2[edge 4lg+r][ch 16nf+lr]; B shared across streams
    f32x4 aA[4], aB[4];
#pragma unroll
    for (int nf=0;nf<4;++nf){
      union{uint4 v; f16x8 h;}q0, q1;
      q0.v = wlds[nf*64 + l];  q1.v = wlds[(4+nf)*64 + l];
      aA[nf] = MFMA(hA0, q0.h, Z4);  aA[nf] = MFMA(hA1, q1.h, aA[nf]);
      aB[nf] = MFMA(hB0, q0.h, Z4);  aB[nf] = MFMA(hB1, q1.h, aB[nf]);
    }
    // BN2 + lrelu -> per-stream transpose buffers (fp16)
#pragma unroll
    for (int nf=0;nf<4;++nf)
#pragma unroll
      for (int r=0;r<4;++r){
        buf[2*w  ][4*lg+r][16*nf+lr] = h2u((_Float16)lrelu(fmaf(a2v[nf], aA[nf][r], c2v[nf])));
        buf[2*w+1][4*lg+r][16*nf+lr] = h2u((_Float16)lrelu(fmaf(a2v[nf], aB[nf][r], c2v[nf])));
      }
    const f16x8 gA0 = *(const f16x8*)&buf[2*w  ][lr][8*lg];
    const f16x8 gA1 = *(const f16x8*)&buf[2*w  ][lr][32+8*lg];
    const f16x8 gB0 = *(const f16x8*)&buf[2*w+1][lr][8*lg];
    const f16x8 gB1 = *(const f16x8*)&buf[2*w+1][lr][32+8*lg];

    f32x4 cA[4], cB[4];
#pragma unroll
    for (int nf=0;nf<4;++nf){
      union{uint4 v; f16x8 h;}q0, q1;
      q0.v = wlds[512 + nf*64 + l];  q1.v = wlds[512 + (4+nf)*64 + l];
      cA[nf] = MFMA(gA0, q0.h, Z4);  cA[nf] = MFMA(gA1, q1.h, cA[nf]);
      cB[nf] = MFMA(gB0, q0.h, Z4);  cB[nf] = MFMA(gB1, q1.h, cB[nf]);
    }

    // segmax over each node's 16 edges; bias after max; residual
#pragma unroll
    for (int nf=0;nf<4;++nf){
      float mA = fmaxf(fmaxf(cA[nf][0],cA[nf][1]), fmaxf(cA[nf][2],cA[nf][3]));
      mA = fmaxf(mA, __shfl_xor(mA,16,64));
      mA = fmaxf(mA, __shfl_xor(mA,32,64));
      float mB = fmaxf(fmaxf(cB[nf][0],cB[nf][1]), fmaxf(cB[nf][2],cB[nf][3]));
      mB = fmaxf(mB, __shfl_xor(mB,16,64));
      mB = fmaxf(mB, __shfl_xor(mB,32,64));
      if (l < 16){
        const float xA = x[(size_t)nA*64 + nf*16 + l];
        out[(size_t)nA*64 + nf*16 + l] = lrelu(mA + bb[nf] + xA);
        const float xB = x[(size_t)nB*64 + nf*16 + l];
        out[(size_t)nB*64 + nf*16 + l] = lrelu(mB + bb[nf] + xB);
      }
    }
  }
}

extern "C" void kernel_launch(void* const* d_in, const int* in_sizes, int n_in,
                              void* d_out, int out_size, void* d_ws, size_t ws_size,
                              hipStream_t stream) {
  const float* x   = (const float*)d_in[0];
  const int*   ei  = (const int*)d_in[1];
  const float* W1  = (const float*)d_in[2];
  const float* g1  = (const float*)d_in[4];
  const float* be1 = (const float*)d_in[5];
  const float* W2  = (const float*)d_in[6];
  const float* g2  = (const float*)d_in[8];
  const float* be2 = (const float*)d_in[9];
  const float* W3  = (const float*)d_in[10];
  const float* b3  = (const float*)d_in[11];
  float* out = (float*)d_out;

  // ws: coefs 1KB | coefsH 1KB | part1 512KB | part2 512KB | wfb 16KB | U | V
  float*          coefs  = (float*)d_ws;
  unsigned short* coefsH = (unsigned short*)((char*)d_ws + 1024);
  float*          part1  = (float*)((char*)d_ws + 2048);
  float*          part2  = part1 + (size_t)NB2*128;
  unsigned short* wfb    = (unsigned short*)((char*)part2 + (size_t)NB2*128*4);
  unsigned short* Ub     = (unsigned short*)((char*)wfb + 16384);
  unsigned short* Vb     = Ub + (size_t)N_NODES*64;

  kUV<<<(NWT+3)/4, 256, 0, stream>>>(x, W1, Ub, Vb);
  kS1<<<NB2, 256, 0, stream>>>(Ub, Vb, ei, W2, W3, wfb, part1);
  kFin<<<64, 256, 0, stream>>>(part1, g1, be1, coefs, coefsH, NB2);
  kS2<<<NB2, 256, 0, stream>>>(Ub, Vb, ei, (const uint4*)wfb, coefsH, part2);
  kFin<<<64, 256, 0, stream>>>(part2, g2, be2, coefs + 128, coefsH + 128, NB2);
  kS3<<<NB2, 256, 0, stream>>>(Ub, Vb, ei, (const uint4*)wfb, coefsH,
                               coefs + 128, b3, x, out);
}